// Round 1
// baseline (11074.614 us; speedup 1.0000x reference)
//
#include <hip/hip_runtime.h>
#include <hip/hip_bf16.h>
#include <cstdint>

#define B_ 64
#define T_ 1024
#define I_ 128
#define R_ 2048
#define O_ 256

typedef __attribute__((ext_vector_type(8))) __bf16 bf16x8;
typedef __attribute__((ext_vector_type(4))) float f32x4;
typedef unsigned short u16;
typedef unsigned int u32;

__device__ __forceinline__ u16 f2bf(float f) {
    u32 u = __builtin_bit_cast(u32, f);
    u32 r = (u + 0x7FFFu + ((u >> 16) & 1u)) >> 16;
    return (u16)r;
}

__device__ __forceinline__ bf16x8 ldbf8(const u16* p) {
    return *reinterpret_cast<const bf16x8*>(p);
}

// ---- prep kernels -------------------------------------------------------

__global__ void conv_bf16_kernel(const float* __restrict__ src,
                                 u16* __restrict__ dst, int n) {
    int stride = gridDim.x * blockDim.x;
    for (int i = blockIdx.x * blockDim.x + threadIdx.x; i < n; i += stride)
        dst[i] = f2bf(src[i]);
}

__global__ void bias_sum_kernel(const float* __restrict__ a,
                                const float* __restrict__ b,
                                float* __restrict__ c, int n) {
    int i = blockIdx.x * blockDim.x + threadIdx.x;
    if (i < n) c[i] = a[i] + b[i];
}

// in: [B][T][I] f32  ->  X: [T][B][I] bf16
__global__ void transpose_x_kernel(const float* __restrict__ in,
                                   u16* __restrict__ X) {
    const int total = T_ * B_ * I_;
    int stride = gridDim.x * blockDim.x;
    for (int idx = blockIdx.x * blockDim.x + threadIdx.x; idx < total; idx += stride) {
        int i  = idx & (I_ - 1);
        int tb = idx >> 7;          // I_=128
        int b  = tb & (B_ - 1);
        int t  = tb >> 6;           // B_=64
        X[idx] = f2bf(in[((size_t)b * T_ + t) * I_ + i]);
    }
}

// ---- recurrent step -----------------------------------------------------
// h_out[b, col] = tanh( X_t[b,:]·Wi[col,:] + h_in[b,:]·Wr[col,:] + bias[col] )
// 512 tiles of 16x16 (4 m-tiles x 128 n-tiles); 256 blocks x 2 waves.
__global__ __launch_bounds__(128) void step_kernel(
    const u16* __restrict__ Wr, const u16* __restrict__ Wi,
    const u16* __restrict__ X, const float* __restrict__ bias,
    const u16* __restrict__ h_in, u16* __restrict__ h_out, int t)
{
    const int lane = threadIdx.x & 63;
    const int wid  = threadIdx.x >> 6;
    const int g    = blockIdx.x * 2 + wid;   // 0..511
    const int m    = g >> 7;                 // 0..3
    const int n    = g & 127;                // 0..127
    const int koff = (lane >> 4) * 8;
    const int b    = m * 16 + (lane & 15);   // A row
    const int col  = n * 16 + (lane & 15);   // B col

    f32x4 acc0 = {0.f,0.f,0.f,0.f};
    f32x4 acc1 = {0.f,0.f,0.f,0.f};
    f32x4 acc2 = {0.f,0.f,0.f,0.f};
    f32x4 acc3 = {0.f,0.f,0.f,0.f};

    // input projection: K = 128 (4 chunks of 32)
    {
        const u16* Ax = X + ((size_t)t * B_ + b) * I_ + koff;
        const u16* Bx = Wi + (size_t)col * I_ + koff;
        acc0 = __builtin_amdgcn_mfma_f32_16x16x32_bf16(ldbf8(Ax +  0), ldbf8(Bx +  0), acc0, 0, 0, 0);
        acc1 = __builtin_amdgcn_mfma_f32_16x16x32_bf16(ldbf8(Ax + 32), ldbf8(Bx + 32), acc1, 0, 0, 0);
        acc2 = __builtin_amdgcn_mfma_f32_16x16x32_bf16(ldbf8(Ax + 64), ldbf8(Bx + 64), acc2, 0, 0, 0);
        acc3 = __builtin_amdgcn_mfma_f32_16x16x32_bf16(ldbf8(Ax + 96), ldbf8(Bx + 96), acc3, 0, 0, 0);
    }

    // recurrent part: K = 2048 (64 chunks of 32), 4-way acc rotation
    {
        const u16* Ah = h_in + (size_t)b * R_ + koff;
        const u16* Bh = Wr + (size_t)col * R_ + koff;
        #pragma unroll 4
        for (int kc = 0; kc < 64; kc += 4) {
            bf16x8 a0 = ldbf8(Ah + (kc + 0) * 32);
            bf16x8 w0 = ldbf8(Bh + (kc + 0) * 32);
            bf16x8 a1 = ldbf8(Ah + (kc + 1) * 32);
            bf16x8 w1 = ldbf8(Bh + (kc + 1) * 32);
            bf16x8 a2 = ldbf8(Ah + (kc + 2) * 32);
            bf16x8 w2 = ldbf8(Bh + (kc + 2) * 32);
            bf16x8 a3 = ldbf8(Ah + (kc + 3) * 32);
            bf16x8 w3 = ldbf8(Bh + (kc + 3) * 32);
            acc0 = __builtin_amdgcn_mfma_f32_16x16x32_bf16(a0, w0, acc0, 0, 0, 0);
            acc1 = __builtin_amdgcn_mfma_f32_16x16x32_bf16(a1, w1, acc1, 0, 0, 0);
            acc2 = __builtin_amdgcn_mfma_f32_16x16x32_bf16(a2, w2, acc2, 0, 0, 0);
            acc3 = __builtin_amdgcn_mfma_f32_16x16x32_bf16(a3, w3, acc3, 0, 0, 0);
        }
    }

    f32x4 s = acc0 + acc1 + acc2 + acc3;
    const float bs = bias[col];
    #pragma unroll
    for (int i2 = 0; i2 < 4; ++i2) {
        // C/D layout: col = lane&15, row = (lane>>4)*4 + reg  [m89-verified]
        int row = m * 16 + (lane >> 4) * 4 + i2;
        float v = tanhf(s[i2] + bs);
        h_out[(size_t)row * R_ + col] = f2bf(v);
    }
}

// ---- readout ------------------------------------------------------------
// out[b, o] = h[b,:]·Wo[o,:] + b_out[o]   (64 x 256), 64 tiles of 16x16
__global__ __launch_bounds__(128) void readout_kernel(
    const u16* __restrict__ h, const u16* __restrict__ Wo,
    const float* __restrict__ b_out, float* __restrict__ out)
{
    const int lane = threadIdx.x & 63;
    const int wid  = threadIdx.x >> 6;
    const int g    = blockIdx.x * 2 + wid;   // 0..63
    const int m    = g >> 4;                 // 0..3
    const int n    = g & 15;                 // 0..15
    const int koff = (lane >> 4) * 8;
    const int b    = m * 16 + (lane & 15);
    const int col  = n * 16 + (lane & 15);

    f32x4 acc0 = {0.f,0.f,0.f,0.f};
    f32x4 acc1 = {0.f,0.f,0.f,0.f};
    f32x4 acc2 = {0.f,0.f,0.f,0.f};
    f32x4 acc3 = {0.f,0.f,0.f,0.f};

    const u16* Ah = h + (size_t)b * R_ + koff;
    const u16* Bh = Wo + (size_t)col * R_ + koff;
    #pragma unroll 4
    for (int kc = 0; kc < 64; kc += 4) {
        acc0 = __builtin_amdgcn_mfma_f32_16x16x32_bf16(ldbf8(Ah + (kc + 0) * 32), ldbf8(Bh + (kc + 0) * 32), acc0, 0, 0, 0);
        acc1 = __builtin_amdgcn_mfma_f32_16x16x32_bf16(ldbf8(Ah + (kc + 1) * 32), ldbf8(Bh + (kc + 1) * 32), acc1, 0, 0, 0);
        acc2 = __builtin_amdgcn_mfma_f32_16x16x32_bf16(ldbf8(Ah + (kc + 2) * 32), ldbf8(Bh + (kc + 2) * 32), acc2, 0, 0, 0);
        acc3 = __builtin_amdgcn_mfma_f32_16x16x32_bf16(ldbf8(Ah + (kc + 3) * 32), ldbf8(Bh + (kc + 3) * 32), acc3, 0, 0, 0);
    }

    f32x4 s = acc0 + acc1 + acc2 + acc3;
    const float bo = b_out[col];
    #pragma unroll
    for (int i2 = 0; i2 < 4; ++i2) {
        int row = m * 16 + (lane >> 4) * 4 + i2;
        out[(size_t)row * O_ + col] = s[i2] + bo;
    }
}

// ---- launch -------------------------------------------------------------

extern "C" void kernel_launch(void* const* d_in, const int* in_sizes, int n_in,
                              void* d_out, int out_size, void* d_ws, size_t ws_size,
                              hipStream_t stream) {
    const float* in    = (const float*)d_in[0];
    const float* Winw  = (const float*)d_in[1];
    const float* Winb  = (const float*)d_in[2];
    const float* Wresw = (const float*)d_in[3];
    const float* Wresb = (const float*)d_in[4];
    const float* Woutw = (const float*)d_in[5];
    const float* Woutb = (const float*)d_in[6];
    float* out = (float*)d_out;

    char* ws = (char*)d_ws;
    u16*   Wr   = (u16*)(ws);                      // 2048*2048*2 = 8388608
    u16*   Wi   = (u16*)(ws + 8388608);            // 2048*128*2  = 524288
    u16*   Wo   = (u16*)(ws + 8912896);            // 256*2048*2  = 1048576
    float* bias = (float*)(ws + 9961472);          // 2048*4      = 8192
    u16*   X    = (u16*)(ws + 9969664);            // 1024*64*128*2 = 16777216
    u16*   hA   = (u16*)(ws + 26746880);           // 64*2048*2   = 262144
    u16*   hB   = (u16*)(ws + 27009024);           // 64*2048*2   = 262144
    // total: 27271168 bytes (~26 MB)

    conv_bf16_kernel<<<2048, 256, 0, stream>>>(Wresw, Wr, R_ * R_);
    conv_bf16_kernel<<<256, 256, 0, stream>>>(Winw, Wi, R_ * I_);
    conv_bf16_kernel<<<512, 256, 0, stream>>>(Woutw, Wo, O_ * R_);
    bias_sum_kernel<<<8, 256, 0, stream>>>(Winb, Wresb, bias, R_);
    transpose_x_kernel<<<4096, 256, 0, stream>>>(in, X);
    hipMemsetAsync(hA, 0, (size_t)B_ * R_ * sizeof(u16), stream);

    for (int t = 0; t < T_; ++t) {
        const u16* hi = (t & 1) ? hB : hA;
        u16*       ho = (t & 1) ? hA : hB;
        step_kernel<<<256, 128, 0, stream>>>(Wr, Wi, X, bias, hi, ho, t);
    }
    // T_ = 1024 is even -> final h is in hA
    readout_kernel<<<32, 128, 0, stream>>>(hA, Wo, Woutb, out);
}